// Round 8
// baseline (145.604 us; speedup 1.0000x reference)
//
#include <hip/hip_runtime.h>
#include <hip/hip_bf16.h>
#include <stdint.h>

// CausalSelfAttention: x[2,2048,1024] -> qkv -> 16-head causal attn -> proj.
// bf16 MFMA pipeline, fp32 accumulation everywhere.

typedef __attribute__((ext_vector_type(4))) float  f32x4;
typedef __attribute__((ext_vector_type(8))) __bf16 bf16x8;
typedef __attribute__((ext_vector_type(4))) short  s16x4;
typedef __attribute__((ext_vector_type(8))) short  s16x8;

#define MFMA(a, b, c) __builtin_amdgcn_mfma_f32_16x16x32_bf16((a), (b), (c), 0, 0, 0)

// 16x16x16 bf16 MFMA: device pass has it on gfx950; host pass only parses.
#if defined(__HIP_DEVICE_COMPILE__)
#define MFMA16(a, b, c) __builtin_amdgcn_mfma_f32_16x16x16bf16_1k((a), (b), (c), 0, 0, 0)
#else
#define MFMA16(a, b, c) (c)
#endif

// f32 -> bf16 RTNE. Device: native cast so the compiler can fuse pairs into
// v_cvt_pk_bf16_f32. Host: parse-only bit-twiddle equivalent.
__device__ __forceinline__ short f2bf(float x) {
#if defined(__HIP_DEVICE_COMPILE__)
  union { __bf16 b; short s; } u; u.b = (__bf16)x; return u.s;
#else
  union { float f; unsigned u; } v; v.f = x;
  unsigned r = v.u + 0x7FFFu + ((v.u >> 16) & 1u);
  return (short)(r >> 16);
#endif
}

__device__ __forceinline__ void gload16(const void* gptr, void* lptr) {
  __builtin_amdgcn_global_load_lds(
      (const __attribute__((address_space(1))) void*)gptr,
      (__attribute__((address_space(3))) void*)lptr, 16, 0, 0);
}

// ---------------- conversion kernels ----------------

__global__ __launch_bounds__(256) void k_f32_to_bf16(const float* __restrict__ in,
                                                     short* __restrict__ out, int n) {
  int i = (blockIdx.x * 256 + threadIdx.x) * 4;
  if (i >= n) return;
  float4 v = *(const float4*)(in + i);
  s16x4 o;
  o[0] = f2bf(v.x); o[1] = f2bf(v.y); o[2] = f2bf(v.z); o[3] = f2bf(v.w);
  *(s16x4*)(out + i) = o;
}

// W [R][C] fp32 row-major  ->  Wt [C][R] bf16 (i.e. [n][k] layout for GEMM B^T)
__global__ __launch_bounds__(256) void k_transpose_bf(const float* __restrict__ W,
                                                      short* __restrict__ Wt, int R, int C) {
  __shared__ float tile[32][33];
  const int tx = threadIdx.x & 31, ty = threadIdx.x >> 5;  // ty 0..7
  const int bx = blockIdx.x * 32, by = blockIdx.y * 32;
#pragma unroll
  for (int i = 0; i < 4; ++i)
    tile[ty + i * 8][tx] = W[(long)(by + ty + i * 8) * C + bx + tx];
  __syncthreads();
#pragma unroll
  for (int i = 0; i < 4; ++i)
    Wt[(long)(bx + ty + i * 8) * R + by + tx] = f2bf(tile[tx][ty + i * 8]);
}

// ---------------- QKV GEMM: 256x256 tile, 4-phase/K-step (8-phase template) --
// BK=64 split into 2 kk-halves of 32; half-tile = one matrix's kk-half
// (256 rows x 32 k = 16 KB, 2 gload_lds/thread). 512 threads = 8 waves
// (2M x 4N), per-wave output 128x64, acc[8][4]. LDS 128 KiB (2 dbuf).
// Phase p (kk=p>>1, mih=p&1): stage half_p(t+1) -> vmcnt(6) -> barrier ->
// ds_read (4 A-frags, + 4 B-frags on even phases, held 2 phases in regs) ->
// setprio(1) -> 16 MFMA -> setprio(0).
// vmcnt(6) = 2 loads x 3 halves in flight: retires exactly the half this
// phase reads (staged 4 stage-issues earlier). Tail step drains 6/4/2/0.

#define QKV_PHASE(PH, KK, MIH, TAILVM)                                        \
  {                                                                           \
    if (t + 1 < NT) {                                                         \
      stage_half(nxt, (PH), (t + 1) << 6);                                    \
      asm volatile("s_waitcnt vmcnt(6)" ::: "memory");                        \
    } else {                                                                  \
      asm volatile("s_waitcnt vmcnt(" TAILVM ")" ::: "memory");               \
    }                                                                         \
    __builtin_amdgcn_s_barrier();                                             \
    {                                                                         \
      const short* Ab = &Als[cur][(KK) * 8192 + (wr * 128 + (MIH) * 64 + fr) * 32 + fg * 8]; \
      if ((MIH) == 0) {                                                       \
        const short* Bb = &Bls[cur][(KK) * 8192 + (wc * 64 + fr) * 32 + fg * 8]; \
        _Pragma("unroll")                                                     \
        for (int ni = 0; ni < 4; ++ni) bfr[ni] = *(const bf16x8*)(Bb + ni * 512); \
      }                                                                       \
      bf16x8 af[4];                                                           \
      _Pragma("unroll")                                                       \
      for (int mi = 0; mi < 4; ++mi) af[mi] = *(const bf16x8*)(Ab + mi * 512); \
      __builtin_amdgcn_s_setprio(1);                                          \
      _Pragma("unroll")                                                       \
      for (int mi = 0; mi < 4; ++mi)                                          \
        _Pragma("unroll")                                                     \
        for (int ni = 0; ni < 4; ++ni)                                        \
          acc[(MIH) * 4 + mi][ni] = MFMA(af[mi], bfr[ni], acc[(MIH) * 4 + mi][ni]); \
      __builtin_amdgcn_s_setprio(0);                                          \
    }                                                                         \
  }

__global__ __launch_bounds__(512, 2) void k_gemm_qkv(const short* __restrict__ A,
                                                     const short* __restrict__ Bt,
                                                     const float* __restrict__ bias,
                                                     short* __restrict__ q_out,
                                                     short* __restrict__ k_out,
                                                     short* __restrict__ vt_out) {
  constexpr int K = 1024;
  constexpr int NT = 16;              // K / 64
  __shared__ short Als[2][16384];     // [buf][kk*8192 + row*32 + chunk*8]
  __shared__ short Bls[2][16384];
  const int tid = threadIdx.x;
  const int lane = tid & 63;
  const int w = tid >> 6;
  const int wr = w >> 2, wc = w & 3;  // 2M x 4N wave grid
  const int bm = blockIdx.y * 256, bn = blockIdx.x * 256;
  const int fr = lane & 15, fg = lane >> 4;
  const short* Ag = A + (long)(bm + (tid >> 2)) * K + (tid & 3) * 8;
  const short* Bg = Bt + (long)(bn + (tid >> 2)) * K + (tid & 3) * 8;

  f32x4 acc[8][4];
#pragma unroll
  for (int i = 0; i < 8; ++i)
#pragma unroll
    for (int j = 0; j < 4; ++j) acc[i][j] = (f32x4){0.f, 0.f, 0.f, 0.f};

  auto stage_half = [&](int buf, int p, int kt) {
    const int kk = p >> 1;
    const int off = kt + kk * 32;
    if (p & 1) {
      short* dst = &Bls[buf][kk * 8192 + tid * 8];
      gload16(Bg + off, dst);
      gload16(Bg + 128 * K + off, dst + 4096);
    } else {
      short* dst = &Als[buf][kk * 8192 + tid * 8];
      gload16(Ag + off, dst);
      gload16(Ag + 128 * K + off, dst + 4096);
    }
  };

  // prologue: all 4 halves of tile 0, in steady-state order A-k0,B-k0,A-k1,B-k1
  stage_half(0, 0, 0);
  stage_half(0, 1, 0);
  stage_half(0, 2, 0);
  stage_half(0, 3, 0);

  bf16x8 bfr[4];
  for (int t = 0; t < NT; ++t) {
    const int cur = t & 1, nxt = cur ^ 1;
    QKV_PHASE(0, 0, 0, "6")
    QKV_PHASE(1, 0, 1, "4")
    QKV_PHASE(2, 1, 0, "2")
    QKV_PHASE(3, 1, 1, "0")
  }

  // epilogue: scatter to Q (pre-scaled), K, Vt
  const float QSC = 0.125f * 1.44269504088896341f;  // (1/sqrt(64)) * log2(e)
  const int which = bn >> 10;          // uniform per block (256 | 1024)
#pragma unroll
  for (int mi = 0; mi < 8; ++mi) {
#pragma unroll
    for (int ni = 0; ni < 4; ++ni) {
      const int gcol = bn + wc * 64 + ni * 16 + fr;
      const float bv = bias[gcol];
      const int grow0 = bm + wr * 128 + mi * 16 + fg * 4;
      const int e = gcol & 1023;
      const int h = e >> 6, d = e & 63;
#pragma unroll
      for (int r = 0; r < 4; ++r) {
        const int mrow = grow0 + r;
        const int b = mrow >> 11, s = mrow & 2047;
        const float av = acc[mi][ni][r] + bv;
        if (which == 0)      q_out[((long)(b * 16 + h) * 2048 + s) * 64 + d] = f2bf(av * QSC);
        else if (which == 1) k_out[((long)(b * 16 + h) * 2048 + s) * 64 + d] = f2bf(av);
        else                 vt_out[((long)(b * 16 + h) * 64 + d) * 2048 + s] = f2bf(av);
      }
    }
  }
}

// ---------------- proj GEMM: C[M][N] = A[M][K]*Bt[N][K]^T + bias (fp32 out) --
// 128x128 tile, BK=32, 4 waves. Triple-buffered LDS, counted vmcnt(4).

__global__ __launch_bounds__(256) void k_gemm_proj(const short* __restrict__ A,
                                                   const short* __restrict__ Bt,
                                                   const float* __restrict__ bias,
                                                   int M, int N, int K,
                                                   float* __restrict__ c_out) {
  __shared__ short As[3][4096];
  __shared__ short Bs[3][4096];
  const int tid  = threadIdx.x;
  const int lane = tid & 63;
  const int wave = tid >> 6;
  const int wm = (wave >> 1) * 64, wn = (wave & 1) * 64;
  const int bm = blockIdx.y * 128, bn = blockIdx.x * 128;
  const int sr = tid >> 2, sc = (tid & 3) * 8;
  const short* Ag = A + (long)(bm + sr) * K + sc;
  const short* Bg = Bt + (long)(bn + sr) * K + sc;
  const int fr = lane & 15, fg = lane >> 4;

  f32x4 acc[4][4];
#pragma unroll
  for (int i = 0; i < 4; ++i)
#pragma unroll
    for (int j = 0; j < 4; ++j) acc[i][j] = (f32x4){0.f, 0.f, 0.f, 0.f};

  auto stage = [&](int buf, int kt) {
    gload16(Ag + kt, &As[buf][tid * 8]);
    gload16(Ag + kt + 64 * K, &As[buf][2048 + tid * 8]);
    gload16(Bg + kt, &Bs[buf][tid * 8]);
    gload16(Bg + kt + 64 * K, &Bs[buf][2048 + tid * 8]);
  };
  auto compute = [&](int buf) {
    bf16x8 af[4], bfr[4];
    const short* Ar = &As[buf][(wm + fr) * 32 + fg * 8];
    const short* Br = &Bs[buf][(wn + fr) * 32 + fg * 8];
#pragma unroll
    for (int mi = 0; mi < 4; ++mi) af[mi] = *(const bf16x8*)(Ar + mi * 16 * 32);
#pragma unroll
    for (int ni = 0; ni < 4; ++ni) bfr[ni] = *(const bf16x8*)(Br + ni * 16 * 32);
#pragma unroll
    for (int mi = 0; mi < 4; ++mi)
#pragma unroll
      for (int ni = 0; ni < 4; ++ni)
        acc[mi][ni] = MFMA(af[mi], bfr[ni], acc[mi][ni]);
  };

  const int NT = K >> 5;
  stage(0, 0);
  stage(1, 32);
  for (int t = 0; t < NT - 1; ++t) {
    asm volatile("s_waitcnt vmcnt(4)" ::: "memory");
    __builtin_amdgcn_s_barrier();
    asm volatile("" ::: "memory");
    if (t + 2 < NT) stage((t + 2) % 3, (t + 2) << 5);
    compute(t % 3);
  }
  asm volatile("s_waitcnt vmcnt(0)" ::: "memory");
  __builtin_amdgcn_s_barrier();
  asm volatile("" ::: "memory");
  compute((NT - 1) % 3);

#pragma unroll
  for (int mi = 0; mi < 4; ++mi) {
#pragma unroll
    for (int ni = 0; ni < 4; ++ni) {
      const int gcol  = bn + wn + ni * 16 + fr;
      const float bv  = bias[gcol];
      const int grow0 = bm + wm + mi * 16 + fg * 4;
#pragma unroll
      for (int r = 0; r < 4; ++r)
        c_out[(long)(grow0 + r) * N + gcol] = acc[mi][ni][r] + bv;
    }
  }
}

// ---------------- causal flash attention ----------------
// grid (bh=32, 32 strips of 64 q-rows), 256-thread blocks (4 waves x 16 rows).
// K/V tiles (64 keys) in XOR-swizzled LDS, double-buffered global_load_lds.
// Swapped QK^T (mfma(K,Q)) puts P in the 16x16x16 B-operand layout -> PV from
// registers. Q pre-scaled by 0.125*log2e in the QKV epilogue. l-sum on the
// MFMA pipe via a ones-fragment. Max via v_max3 tree. setprio around MFMA.

__global__ __launch_bounds__(256, 4) void k_attn(const short* __restrict__ Qb,
                                                 const short* __restrict__ Kb,
                                                 const short* __restrict__ Vt,
                                                 short* __restrict__ Y) {
  __shared__ short smem[2][2][4096];   // [buf][0=K,1=V][64 rows][64 shorts]
  const int bh = blockIdx.x;
  const int strip = 31 - blockIdx.y;   // heavy-first dispatch
  const int qw0 = strip * 64;
  const int b = bh >> 4, h = bh & 15;
  const int tid = threadIdx.x;
  const int w = tid >> 6, lane = tid & 63;
  const int ql = lane & 15, g = lane >> 4;
  const short* Kp = Kb + (long)bh * 2048 * 64;
  const short* Vp = Vt + (long)bh * 64 * 2048;
  const short* Qp = Qb + ((long)bh * 2048 + qw0 + w * 16) * 64;

  const bf16x8 qf0 = *(const bf16x8*)(Qp + ql * 64 + g * 8);
  const bf16x8 qf1 = *(const bf16x8*)(Qp + ql * 64 + 32 + g * 8);

  const int sr_ = tid >> 3, sj_ = tid & 7;

  s16x4 ones;
  ones[0] = ones[1] = ones[2] = ones[3] = (short)0x3F80;  // bf16 1.0

  f32x4 o[4];
#pragma unroll
  for (int df = 0; df < 4; ++df) o[df] = (f32x4){0.f, 0.f, 0.f, 0.f};
  f32x4 o_l = (f32x4){0.f, 0.f, 0.f, 0.f};   // row-sum accumulator (l)
  float m = -1e30f;
  const int nt = strip + 1;

  {  // prologue stage of tile 0
#pragma unroll
    for (int j = 0; j < 2; ++j) {
      const int r = j * 32 + sr_;
      const int c = sj_ ^ (r & 7);
      gload16(Kp + (long)r * 64 + c * 8, &smem[0][0][j * 2048 + tid * 8]);
      gload16(Vp + (long)r * 2048 + c * 8, &smem[0][1][j * 2048 + tid * 8]);
    }
  }

  for (int t = 0; t < nt; ++t) {
    const int cur = t & 1;
    __syncthreads();                  // waits own vmcnt -> buf[cur] ready, prev reads done
    if (t + 1 < nt) {                 // issue next-tile stage; lands before next barrier
      const int k0n = (t + 1) * 64;
#pragma unroll
      for (int j = 0; j < 2; ++j) {
        const int r = j * 32 + sr_;
        const int c = sj_ ^ (r & 7);
        gload16(Kp + (long)(k0n + r) * 64 + c * 8, &smem[cur ^ 1][0][j * 2048 + tid * 8]);
        gload16(Vp + (long)r * 2048 + k0n + c * 8, &smem[cur ^ 1][1][j * 2048 + tid * 8]);
      }
    }
    const short* Kl = &smem[cur][0][0];
    const short* Vl = &smem[cur][1][0];
    const bool diag = (t == strip);

    // ---- QK^T from LDS (swizzled b128 reads); scores already exp2-scaled ----
    float z[16];
    __builtin_amdgcn_s_setprio(1);
#pragma unroll
    for (int kf = 0; kf < 4; ++kf) {
      if (!diag || kf <= w) {
        const int r = kf * 16 + ql;
        const bf16x8 ka = *(const bf16x8*)(Kl + r * 64 + ((g ^ (r & 7)) * 8));
        const bf16x8 kb = *(const bf16x8*)(Kl + r * 64 + (((4 + g) ^ (r & 7)) * 8));
        f32x4 zz = (f32x4){0.f, 0.f, 0.f, 0.f};
        zz = MFMA(ka, qf0, zz);       // S^T[k][q], d 0..31
        zz = MFMA(kb, qf1, zz);       // += d 32..63
        if (diag && kf == w) {        // diagonal 16x16 block: per-element mask
#pragma unroll
          for (int r4 = 0; r4 < 4; ++r4)
            z[kf * 4 + r4] = (g * 4 + r4 <= ql) ? zz[r4] : -3.0e38f;
        } else {
#pragma unroll
          for (int r4 = 0; r4 < 4; ++r4) z[kf * 4 + r4] = zz[r4];
        }
      } else {
#pragma unroll
        for (int r4 = 0; r4 < 4; ++r4) z[kf * 4 + r4] = -3.0e38f;
      }
    }
    __builtin_amdgcn_s_setprio(0);

    // ---- max: nested fmaxf -> v_max3 tree, + 2 shfl ----
    const float t1 = fmaxf(fmaxf(z[0], z[1]), z[2]);
    const float t2 = fmaxf(fmaxf(z[3], z[4]), z[5]);
    const float t3 = fmaxf(fmaxf(z[6], z[7]), z[8]);
    const float t4 = fmaxf(fmaxf(z[9], z[10]), z[11]);
    const float t5 = fmaxf(fmaxf(z[12], z[13]), z[14]);
    float tz = fmaxf(fmaxf(fmaxf(t1, t2), t3), fmaxf(fmaxf(t4, t5), z[15]));
    tz = fmaxf(tz, __shfl_xor(tz, 16));
    tz = fmaxf(tz, __shfl_xor(tz, 32));
    // ---- defer-max rescale (T13, log2 domain THR=8) ----
    if (!__all(tz <= m + 8.0f)) {
      const float nm = fmaxf(m, tz);
      const float fac = exp2f(m - nm);
#pragma unroll
      for (int df = 0; df < 4; ++df) o[df] *= fac;
      o_l *= fac;
      m = nm;
    }
    // ---- P = exp2(z - m) straight into bf16 fragments; PV + l via MFMA ----
    __builtin_amdgcn_s_setprio(1);
#pragma unroll
    for (int kf = 0; kf < 4; ++kf) {
      if (!diag || kf <= w) {
        s16x4 pk;
        pk[0] = f2bf(exp2f(z[kf * 4 + 0] - m));
        pk[1] = f2bf(exp2f(z[kf * 4 + 1] - m));
        pk[2] = f2bf(exp2f(z[kf * 4 + 2] - m));
        pk[3] = f2bf(exp2f(z[kf * 4 + 3] - m));
        o_l = MFMA16(ones, pk, o_l);       // row-sum on the matrix pipe
#pragma unroll
        for (int df = 0; df < 4; ++df) {
          const int d = df * 16 + ql;
          const int c = kf * 2 + (g >> 1);
          const s16x4 vk = *(const s16x4*)(Vl + d * 64 + ((c ^ (d & 7)) * 8) + (g & 1) * 4);
          o[df] = MFMA16(vk, pk, o[df]);   // O^T[d][q]
        }
      }
    }
    __builtin_amdgcn_s_setprio(0);
  }

  // ---- epilogue: divide, transpose via LDS overlay, coalesced store ----
  __syncthreads();                    // all waves done reading K/V buffers
  float* ot = (float*)&smem[0][0][0] + w * 1040;   // per-wave 16x65 floats
  const float linv = 1.f / o_l[0];    // every lane holds l for its q=ql
#pragma unroll
  for (int df = 0; df < 4; ++df)
#pragma unroll
    for (int r = 0; r < 4; ++r)
      ot[ql * 65 + df * 16 + g * 4 + r] = o[df][r] * linv;
  const int q2 = lane >> 2, c4 = (lane & 3) * 16;
  short* Yp = Y + ((long)(b * 2048 + qw0 + w * 16 + q2)) * 1024 + h * 64 + c4;
  s16x8 y0, y1;
#pragma unroll
  for (int j = 0; j < 8; ++j) {
    y0[j] = f2bf(ot[q2 * 65 + c4 + j]);
    y1[j] = f2bf(ot[q2 * 65 + c4 + 8 + j]);
  }
  *(s16x8*)Yp = y0;
  *((s16x8*)(Yp + 8)) = y1;
}

// ---------------- launch ----------------

extern "C" void kernel_launch(void* const* d_in, const int* in_sizes, int n_in,
                              void* d_out, int out_size, void* d_ws, size_t ws_size,
                              hipStream_t stream) {
  const float* x      = (const float*)d_in[0];
  const float* W_attn = (const float*)d_in[1];
  const float* b_attn = (const float*)d_in[2];
  const float* W_proj = (const float*)d_in[3];
  const float* b_proj = (const float*)d_in[4];
  float* out = (float*)d_out;

  char* ws = (char*)d_ws;
  short* x_bf = (short*)(ws);                    //  8 MB  [4096][1024]
  short* Wt_a = (short*)(ws + 8388608);          //  6 MB  [3072][1024]
  short* Wt_p = (short*)(ws + 14680064);         //  2 MB  [1024][1024]
  short* Qb   = (short*)(ws + 16777216);         //  8 MB  [2,16,2048,64]
  short* Kb   = (short*)(ws + 25165824);         //  8 MB  [2,16,2048,64]
  short* Vtb  = (short*)(ws + 33554432);         //  8 MB  [2,16,64,2048]
  short* y_bf = (short*)(ws + 41943040);         //  8 MB  [4096][1024]

  k_f32_to_bf16<<<4096, 256, 0, stream>>>(x, x_bf, 4194304);
  k_transpose_bf<<<dim3(96, 32), 256, 0, stream>>>(W_attn, Wt_a, 1024, 3072);
  k_transpose_bf<<<dim3(32, 32), 256, 0, stream>>>(W_proj, Wt_p, 1024, 1024);
  k_gemm_qkv<<<dim3(12, 16), 512, 0, stream>>>(x_bf, Wt_a, b_attn, Qb, Kb, Vtb);
  k_attn<<<dim3(32, 32), 256, 0, stream>>>(Qb, Kb, Vtb, y_bf);
  k_gemm_proj<<<dim3(8, 32), 256, 0, stream>>>(y_bf, Wt_p, b_proj, 4096, 1024, 1024, out);
}

// Round 9
// 143.496 us; speedup vs baseline: 1.0147x; 1.0147x over previous
//
#include <hip/hip_runtime.h>
#include <hip/hip_bf16.h>
#include <stdint.h>

// CausalSelfAttention: x[2,2048,1024] -> qkv -> 16-head causal attn -> proj.
// bf16 MFMA pipeline, fp32 accumulation everywhere.

typedef __attribute__((ext_vector_type(4))) float  f32x4;
typedef __attribute__((ext_vector_type(8))) __bf16 bf16x8;
typedef __attribute__((ext_vector_type(4))) short  s16x4;
typedef __attribute__((ext_vector_type(8))) short  s16x8;

#define MFMA(a, b, c) __builtin_amdgcn_mfma_f32_16x16x32_bf16((a), (b), (c), 0, 0, 0)

// 16x16x16 bf16 MFMA: device pass has it on gfx950; host pass only parses.
#if defined(__HIP_DEVICE_COMPILE__)
#define MFMA16(a, b, c) __builtin_amdgcn_mfma_f32_16x16x16bf16_1k((a), (b), (c), 0, 0, 0)
#else
#define MFMA16(a, b, c) (c)
#endif

// f32 -> bf16 RTNE. Device: native cast so the compiler can fuse pairs into
// v_cvt_pk_bf16_f32. Host: parse-only bit-twiddle equivalent.
__device__ __forceinline__ short f2bf(float x) {
#if defined(__HIP_DEVICE_COMPILE__)
  union { __bf16 b; short s; } u; u.b = (__bf16)x; return u.s;
#else
  union { float f; unsigned u; } v; v.f = x;
  unsigned r = v.u + 0x7FFFu + ((v.u >> 16) & 1u);
  return (short)(r >> 16);
#endif
}

__device__ __forceinline__ void gload16(const void* gptr, void* lptr) {
  __builtin_amdgcn_global_load_lds(
      (const __attribute__((address_space(1))) void*)gptr,
      (__attribute__((address_space(3))) void*)lptr, 16, 0, 0);
}

// ---------------- conversion kernels ----------------

__global__ __launch_bounds__(256) void k_f32_to_bf16(const float* __restrict__ in,
                                                     short* __restrict__ out, int n) {
  int i = (blockIdx.x * 256 + threadIdx.x) * 4;
  if (i >= n) return;
  float4 v = *(const float4*)(in + i);
  s16x4 o;
  o[0] = f2bf(v.x); o[1] = f2bf(v.y); o[2] = f2bf(v.z); o[3] = f2bf(v.w);
  *(s16x4*)(out + i) = o;
}

// W [R][C] fp32 row-major  ->  Wt [C][R] bf16 (i.e. [n][k] layout for GEMM B^T)
__global__ __launch_bounds__(256) void k_transpose_bf(const float* __restrict__ W,
                                                      short* __restrict__ Wt, int R, int C) {
  __shared__ float tile[32][33];
  const int tx = threadIdx.x & 31, ty = threadIdx.x >> 5;  // ty 0..7
  const int bx = blockIdx.x * 32, by = blockIdx.y * 32;
#pragma unroll
  for (int i = 0; i < 4; ++i)
    tile[ty + i * 8][tx] = W[(long)(by + ty + i * 8) * C + bx + tx];
  __syncthreads();
#pragma unroll
  for (int i = 0; i < 4; ++i)
    Wt[(long)(bx + ty + i * 8) * R + by + tx] = f2bf(tile[tx][ty + i * 8]);
}

// ---------------- QKV GEMM: 256x256 tile, BK=64, 4 phases/K-step ------------
// 512 threads = 8 waves (2M x 4N), per-wave output 128x64, acc[8][4].
// LDS: per matrix per buffer [256 rows][64 shorts] (row = full BK), 16B chunks
// at slot c ^ (row&7) -- conflict-free ds_read_b128 (2-way max). Staged via
// pre-swizzled global source + LINEAR gload_lds dest (rule #21).
// Schedule per K-tile t (phases p0..p3 = (kk,mih) = 00,01,10,11):
//   p0: vmcnt(0) [drains tile-t stages, youngest >=2 phases old] -> barrier ->
//       ds_read A+B frags -> issue stage A(t+1) -> 16 MFMA
//   p1: barrier -> ds_read A frags -> 16 MFMA     (B frags held in regs)
//   p2: barrier -> ds_read A+B -> issue stage B(t+1) -> 16 MFMA
//   p3: barrier -> ds_read A -> 16 MFMA
// Stages write buf^1; issued POST-barrier so barrier semantics separate them
// from any straggler reads of the same buffer (WAR-safe).

#define QKV_COMPUTE(KK, MIH, DOSTAGE)                                          \
  {                                                                            \
    if ((MIH) == 0) {                                                          \
      _Pragma("unroll")                                                        \
      for (int ni = 0; ni < 4; ++ni) {                                         \
        const int row = wc * 64 + ni * 16 + fr;                                \
        bfr[ni] = *(const bf16x8*)&Bls[cur][row * 64 + ((((KK)*4 + fg) ^ (fr & 7)) * 8)]; \
      }                                                                        \
    }                                                                          \
    bf16x8 af[4];                                                              \
    _Pragma("unroll")                                                          \
    for (int mi = 0; mi < 4; ++mi) {                                           \
      const int row = wr * 128 + (MIH) * 64 + mi * 16 + fr;                    \
      af[mi] = *(const bf16x8*)&Als[cur][row * 64 + ((((KK)*4 + fg) ^ (fr & 7)) * 8)]; \
    }                                                                          \
    DOSTAGE;                                                                   \
    __builtin_amdgcn_s_setprio(1);                                             \
    _Pragma("unroll")                                                          \
    for (int mi = 0; mi < 4; ++mi)                                             \
      _Pragma("unroll")                                                        \
      for (int ni = 0; ni < 4; ++ni)                                           \
        acc[(MIH)*4 + mi][ni] = MFMA(af[mi], bfr[ni], acc[(MIH)*4 + mi][ni]);  \
    __builtin_amdgcn_s_setprio(0);                                             \
  }

__global__ __launch_bounds__(512, 1) void k_gemm_qkv(const short* __restrict__ A,
                                                     const short* __restrict__ Bt,
                                                     const float* __restrict__ bias,
                                                     short* __restrict__ q_out,
                                                     short* __restrict__ k_out,
                                                     short* __restrict__ vt_out) {
  constexpr int K = 1024;
  constexpr int NT = 16;              // K / 64
  __shared__ short Als[2][16384];     // [buf][row*64 + slot*8], slot = c ^ (row&7)
  __shared__ short Bls[2][16384];
  const int tid = threadIdx.x;
  const int lane = tid & 63;
  const int w = tid >> 6;
  const int wr = w >> 2, wc = w & 3;  // 2M x 4N wave grid
  const int bm = blockIdx.y * 256, bn = blockIdx.x * 256;
  const int fr = lane & 15, fg = lane >> 4;

  // staging: thread covers dest chunks tid, tid+512, tid+1024, tid+1536
  // (rows rt, rt+64, rt+128, rt+192; slot tid&7). Source chunk for slot s,
  // row r: c = s ^ (r&7); r&7 == rt&7 for all four. Dest offset = tid*8
  // shorts + q*4096 -> lane-contiguous per wave (lane*16 B) as required.
  const int rt = tid >> 3;
  const int csw = ((tid & 7) ^ (rt & 7)) * 8;   // pre-swizzled source k-offset
  const short* Agb = A + (long)(bm + rt) * K + csw;
  const short* Bgb = Bt + (long)(bn + rt) * K + csw;

  f32x4 acc[8][4];
#pragma unroll
  for (int i = 0; i < 8; ++i)
#pragma unroll
    for (int j = 0; j < 4; ++j) acc[i][j] = (f32x4){0.f, 0.f, 0.f, 0.f};

  auto stageA = [&](int buf, int t1) {
    const long kt = (long)t1 << 6;
#pragma unroll
    for (int q = 0; q < 4; ++q)
      gload16(Agb + kt + (long)q * (64 * K), &Als[buf][q * 4096 + tid * 8]);
  };
  auto stageB = [&](int buf, int t1) {
    const long kt = (long)t1 << 6;
#pragma unroll
    for (int q = 0; q < 4; ++q)
      gload16(Bgb + kt + (long)q * (64 * K), &Bls[buf][q * 4096 + tid * 8]);
  };

  // prologue: tile 0 into buf 0
  stageA(0, 0);
  stageB(0, 0);

  bf16x8 bfr[4];
  for (int t = 0; t < NT; ++t) {
    const int cur = t & 1, nxt = cur ^ 1;
    const bool pre = (t + 1 < NT);
    // phase 0 (kk0, mih0)
    asm volatile("s_waitcnt vmcnt(0)" ::: "memory");
    __builtin_amdgcn_s_barrier();
    QKV_COMPUTE(0, 0, { if (pre) stageA(nxt, t + 1); })
    // phase 1 (kk0, mih1)
    __builtin_amdgcn_s_barrier();
    QKV_COMPUTE(0, 1, {})
    // phase 2 (kk1, mih0)
    __builtin_amdgcn_s_barrier();
    QKV_COMPUTE(1, 0, { if (pre) stageB(nxt, t + 1); })
    // phase 3 (kk1, mih1)
    __builtin_amdgcn_s_barrier();
    QKV_COMPUTE(1, 1, {})
  }

  // epilogue: scatter to Q (pre-scaled), K, Vt
  const float QSC = 0.125f * 1.44269504088896341f;  // (1/sqrt(64)) * log2(e)
  const int which = bn >> 10;          // uniform per block (256 | 1024)
#pragma unroll
  for (int mi = 0; mi < 8; ++mi) {
#pragma unroll
    for (int ni = 0; ni < 4; ++ni) {
      const int gcol = bn + wc * 64 + ni * 16 + fr;
      const float bv = bias[gcol];
      const int grow0 = bm + wr * 128 + mi * 16 + fg * 4;
      const int e = gcol & 1023;
      const int h = e >> 6, d = e & 63;
#pragma unroll
      for (int r = 0; r < 4; ++r) {
        const int mrow = grow0 + r;
        const int b = mrow >> 11, s = mrow & 2047;
        const float av = acc[mi][ni][r] + bv;
        if (which == 0)      q_out[((long)(b * 16 + h) * 2048 + s) * 64 + d] = f2bf(av * QSC);
        else if (which == 1) k_out[((long)(b * 16 + h) * 2048 + s) * 64 + d] = f2bf(av);
        else                 vt_out[((long)(b * 16 + h) * 64 + d) * 2048 + s] = f2bf(av);
      }
    }
  }
}

// ---------------- proj GEMM: C[M][N] = A[M][K]*Bt[N][K]^T + bias (fp32 out) --
// 128x128 tile, BK=32, 4 waves. Triple-buffered LDS, counted vmcnt(4).

__global__ __launch_bounds__(256) void k_gemm_proj(const short* __restrict__ A,
                                                   const short* __restrict__ Bt,
                                                   const float* __restrict__ bias,
                                                   int M, int N, int K,
                                                   float* __restrict__ c_out) {
  __shared__ short As[3][4096];
  __shared__ short Bs[3][4096];
  const int tid  = threadIdx.x;
  const int lane = tid & 63;
  const int wave = tid >> 6;
  const int wm = (wave >> 1) * 64, wn = (wave & 1) * 64;
  const int bm = blockIdx.y * 128, bn = blockIdx.x * 128;
  const int sr = tid >> 2, sc = (tid & 3) * 8;
  const short* Ag = A + (long)(bm + sr) * K + sc;
  const short* Bg = Bt + (long)(bn + sr) * K + sc;
  const int fr = lane & 15, fg = lane >> 4;

  f32x4 acc[4][4];
#pragma unroll
  for (int i = 0; i < 4; ++i)
#pragma unroll
    for (int j = 0; j < 4; ++j) acc[i][j] = (f32x4){0.f, 0.f, 0.f, 0.f};

  auto stage = [&](int buf, int kt) {
    gload16(Ag + kt, &As[buf][tid * 8]);
    gload16(Ag + kt + 64 * K, &As[buf][2048 + tid * 8]);
    gload16(Bg + kt, &Bs[buf][tid * 8]);
    gload16(Bg + kt + 64 * K, &Bs[buf][2048 + tid * 8]);
  };
  auto compute = [&](int buf) {
    bf16x8 af[4], bfr[4];
    const short* Ar = &As[buf][(wm + fr) * 32 + fg * 8];
    const short* Br = &Bs[buf][(wn + fr) * 32 + fg * 8];
#pragma unroll
    for (int mi = 0; mi < 4; ++mi) af[mi] = *(const bf16x8*)(Ar + mi * 16 * 32);
#pragma unroll
    for (int ni = 0; ni < 4; ++ni) bfr[ni] = *(const bf16x8*)(Br + ni * 16 * 32);
#pragma unroll
    for (int mi = 0; mi < 4; ++mi)
#pragma unroll
      for (int ni = 0; ni < 4; ++ni)
        acc[mi][ni] = MFMA(af[mi], bfr[ni], acc[mi][ni]);
  };

  const int NT = K >> 5;
  stage(0, 0);
  stage(1, 32);
  for (int t = 0; t < NT - 1; ++t) {
    asm volatile("s_waitcnt vmcnt(4)" ::: "memory");
    __builtin_amdgcn_s_barrier();
    asm volatile("" ::: "memory");
    if (t + 2 < NT) stage((t + 2) % 3, (t + 2) << 5);
    compute(t % 3);
  }
  asm volatile("s_waitcnt vmcnt(0)" ::: "memory");
  __builtin_amdgcn_s_barrier();
  asm volatile("" ::: "memory");
  compute((NT - 1) % 3);

#pragma unroll
  for (int mi = 0; mi < 4; ++mi) {
#pragma unroll
    for (int ni = 0; ni < 4; ++ni) {
      const int gcol  = bn + wn + ni * 16 + fr;
      const float bv  = bias[gcol];
      const int grow0 = bm + wm + mi * 16 + fg * 4;
#pragma unroll
      for (int r = 0; r < 4; ++r)
        c_out[(long)(grow0 + r) * N + gcol] = acc[mi][ni][r] + bv;
    }
  }
}

// ---------------- causal flash attention ----------------
// grid (bh=32, 32 strips of 64 q-rows), 256-thread blocks (4 waves x 16 rows).
// K/V tiles (64 keys) in XOR-swizzled LDS, double-buffered global_load_lds.
// Swapped QK^T (mfma(K,Q)) puts P in the 16x16x16 B-operand layout -> PV from
// registers. Q pre-scaled by 0.125*log2e in the QKV epilogue. l-sum on the
// MFMA pipe via a ones-fragment. Max via v_max3 tree. setprio around MFMA.

__global__ __launch_bounds__(256, 4) void k_attn(const short* __restrict__ Qb,
                                                 const short* __restrict__ Kb,
                                                 const short* __restrict__ Vt,
                                                 short* __restrict__ Y) {
  __shared__ short smem[2][2][4096];   // [buf][0=K,1=V][64 rows][64 shorts]
  const int bh = blockIdx.x;
  const int strip = 31 - blockIdx.y;   // heavy-first dispatch
  const int qw0 = strip * 64;
  const int b = bh >> 4, h = bh & 15;
  const int tid = threadIdx.x;
  const int w = tid >> 6, lane = tid & 63;
  const int ql = lane & 15, g = lane >> 4;
  const short* Kp = Kb + (long)bh * 2048 * 64;
  const short* Vp = Vt + (long)bh * 64 * 2048;
  const short* Qp = Qb + ((long)bh * 2048 + qw0 + w * 16) * 64;

  const bf16x8 qf0 = *(const bf16x8*)(Qp + ql * 64 + g * 8);
  const bf16x8 qf1 = *(const bf16x8*)(Qp + ql * 64 + 32 + g * 8);

  const int sr_ = tid >> 3, sj_ = tid & 7;

  s16x4 ones;
  ones[0] = ones[1] = ones[2] = ones[3] = (short)0x3F80;  // bf16 1.0

  f32x4 o[4];
#pragma unroll
  for (int df = 0; df < 4; ++df) o[df] = (f32x4){0.f, 0.f, 0.f, 0.f};
  f32x4 o_l = (f32x4){0.f, 0.f, 0.f, 0.f};   // row-sum accumulator (l)
  float m = -1e30f;
  const int nt = strip + 1;

  {  // prologue stage of tile 0
#pragma unroll
    for (int j = 0; j < 2; ++j) {
      const int r = j * 32 + sr_;
      const int c = sj_ ^ (r & 7);
      gload16(Kp + (long)r * 64 + c * 8, &smem[0][0][j * 2048 + tid * 8]);
      gload16(Vp + (long)r * 2048 + c * 8, &smem[0][1][j * 2048 + tid * 8]);
    }
  }

  for (int t = 0; t < nt; ++t) {
    const int cur = t & 1;
    __syncthreads();                  // waits own vmcnt -> buf[cur] ready, prev reads done
    if (t + 1 < nt) {                 // issue next-tile stage; lands before next barrier
      const int k0n = (t + 1) * 64;
#pragma unroll
      for (int j = 0; j < 2; ++j) {
        const int r = j * 32 + sr_;
        const int c = sj_ ^ (r & 7);
        gload16(Kp + (long)(k0n + r) * 64 + c * 8, &smem[cur ^ 1][0][j * 2048 + tid * 8]);
        gload16(Vp + (long)r * 2048 + k0n + c * 8, &smem[cur ^ 1][1][j * 2048 + tid * 8]);
      }
    }
    const short* Kl = &smem[cur][0][0];
    const short* Vl = &smem[cur][1][0];
    const bool diag = (t == strip);

    // ---- QK^T from LDS (swizzled b128 reads); scores already exp2-scaled ----
    float z[16];
    __builtin_amdgcn_s_setprio(1);
#pragma unroll
    for (int kf = 0; kf < 4; ++kf) {
      if (!diag || kf <= w) {
        const int r = kf * 16 + ql;
        const bf16x8 ka = *(const bf16x8*)(Kl + r * 64 + ((g ^ (r & 7)) * 8));
        const bf16x8 kb = *(const bf16x8*)(Kl + r * 64 + (((4 + g) ^ (r & 7)) * 8));
        f32x4 zz = (f32x4){0.f, 0.f, 0.f, 0.f};
        zz = MFMA(ka, qf0, zz);       // S^T[k][q], d 0..31
        zz = MFMA(kb, qf1, zz);       // += d 32..63
        if (diag && kf == w) {        // diagonal 16x16 block: per-element mask
#pragma unroll
          for (int r4 = 0; r4 < 4; ++r4)
            z[kf * 4 + r4] = (g * 4 + r4 <= ql) ? zz[r4] : -3.0e38f;
        } else {
#pragma unroll
          for (int r4 = 0; r4 < 4; ++r4) z[kf * 4 + r4] = zz[r4];
        }
      } else {
#pragma unroll
        for (int r4 = 0; r4 < 4; ++r4) z[kf * 4 + r4] = -3.0e38f;
      }
    }
    __builtin_amdgcn_s_setprio(0);

    // ---- max: nested fmaxf -> v_max3 tree, + 2 shfl ----
    const float t1 = fmaxf(fmaxf(z[0], z[1]), z[2]);
    const float t2 = fmaxf(fmaxf(z[3], z[4]), z[5]);
    const float t3 = fmaxf(fmaxf(z[6], z[7]), z[8]);
    const float t4 = fmaxf(fmaxf(z[9], z[10]), z[11]);
    const float t5 = fmaxf(fmaxf(z[12], z[13]), z[14]);
    float tz = fmaxf(fmaxf(fmaxf(t1, t2), t3), fmaxf(fmaxf(t4, t5), z[15]));
    tz = fmaxf(tz, __shfl_xor(tz, 16));
    tz = fmaxf(tz, __shfl_xor(tz, 32));
    // ---- defer-max rescale (T13, log2 domain THR=8) ----
    if (!__all(tz <= m + 8.0f)) {
      const float nm = fmaxf(m, tz);
      const float fac = exp2f(m - nm);
#pragma unroll
      for (int df = 0; df < 4; ++df) o[df] *= fac;
      o_l *= fac;
      m = nm;
    }
    // ---- P = exp2(z - m) straight into bf16 fragments; PV + l via MFMA ----
    __builtin_amdgcn_s_setprio(1);
#pragma unroll
    for (int kf = 0; kf < 4; ++kf) {
      if (!diag || kf <= w) {
        s16x4 pk;
        pk[0] = f2bf(exp2f(z[kf * 4 + 0] - m));
        pk[1] = f2bf(exp2f(z[kf * 4 + 1] - m));
        pk[2] = f2bf(exp2f(z[kf * 4 + 2] - m));
        pk[3] = f2bf(exp2f(z[kf * 4 + 3] - m));
        o_l = MFMA16(ones, pk, o_l);       // row-sum on the matrix pipe
#pragma unroll
        for (int df = 0; df < 4; ++df) {
          const int d = df * 16 + ql;
          const int c = kf * 2 + (g >> 1);
          const s16x4 vk = *(const s16x4*)(Vl + d * 64 + ((c ^ (d & 7)) * 8) + (g & 1) * 4);
          o[df] = MFMA16(vk, pk, o[df]);   // O^T[d][q]
        }
      }
    }
    __builtin_amdgcn_s_setprio(0);
  }

  // ---- epilogue: divide, transpose via LDS overlay, coalesced store ----
  __syncthreads();                    // all waves done reading K/V buffers
  float* ot = (float*)&smem[0][0][0] + w * 1040;   // per-wave 16x65 floats
  const float linv = 1.f / o_l[0];    // every lane holds l for its q=ql
#pragma unroll
  for (int df = 0; df < 4; ++df)
#pragma unroll
    for (int r = 0; r < 4; ++r)
      ot[ql * 65 + df * 16 + g * 4 + r] = o[df][r] * linv;
  const int q2 = lane >> 2, c4 = (lane & 3) * 16;
  short* Yp = Y + ((long)(b * 2048 + qw0 + w * 16 + q2)) * 1024 + h * 64 + c4;
  s16x8 y0, y1;
#pragma unroll
  for (int j = 0; j < 8; ++j) {
    y0[j] = f2bf(ot[q2 * 65 + c4 + j]);
    y1[j] = f2bf(ot[q2 * 65 + c4 + 8 + j]);
  }
  *(s16x8*)Yp = y0;
  *((s16x8*)(Yp + 8)) = y1;
}

// ---------------- launch ----------------

extern "C" void kernel_launch(void* const* d_in, const int* in_sizes, int n_in,
                              void* d_out, int out_size, void* d_ws, size_t ws_size,
                              hipStream_t stream) {
  const float* x      = (const float*)d_in[0];
  const float* W_attn = (const float*)d_in[1];
  const float* b_attn = (const float*)d_in[2];
  const float* W_proj = (const float*)d_in[3];
  const float* b_proj = (const float*)d_in[4];
  float* out = (float*)d_out;

  char* ws = (char*)d_ws;
  short* x_bf = (short*)(ws);                    //  8 MB  [4096][1024]
  short* Wt_a = (short*)(ws + 8388608);          //  6 MB  [3072][1024]
  short* Wt_p = (short*)(ws + 14680064);         //  2 MB  [1024][1024]
  short* Qb   = (short*)(ws + 16777216);         //  8 MB  [2,16,2048,64]
  short* Kb   = (short*)(ws + 25165824);         //  8 MB  [2,16,2048,64]
  short* Vtb  = (short*)(ws + 33554432);         //  8 MB  [2,16,64,2048]
  short* y_bf = (short*)(ws + 41943040);         //  8 MB  [4096][1024]

  k_f32_to_bf16<<<4096, 256, 0, stream>>>(x, x_bf, 4194304);
  k_transpose_bf<<<dim3(96, 32), 256, 0, stream>>>(W_attn, Wt_a, 1024, 3072);
  k_transpose_bf<<<dim3(32, 32), 256, 0, stream>>>(W_proj, Wt_p, 1024, 1024);
  k_gemm_qkv<<<dim3(12, 16), 512, 0, stream>>>(x_bf, Wt_a, b_attn, Qb, Kb, Vtb);
  k_attn<<<dim3(32, 32), 256, 0, stream>>>(Qb, Kb, Vtb, y_bf);
  k_gemm_proj<<<dim3(8, 32), 256, 0, stream>>>(y_bf, Wt_p, b_proj, 4096, 1024, 1024, out);
}